// Round 15
// baseline (21410.110 us; speedup 1.0000x reference)
//
#include <hip/hip_runtime.h>

#define H 512
#define W4 4
#define RINGN 8
#define NWG 128
#define HS 4          // H / NWG
#define NTH 256

// ---------- helpers ----------
__device__ __forceinline__ float sigf(float x){ return 1.f/(1.f+__expf(-x)); }
__device__ __forceinline__ float tanhft(float x){
  float t = __expf(-2.f*fabsf(x));      // never overflows
  float r = (1.f - t)/(1.f + t);
  return copysignf(r, x);
}
// swizzled LDS element index for column-major weight slices
__device__ __forceinline__ int swz(int dd, int k){
  return (dd << 9) | ((((k >> 2) ^ (dd & 7)) << 2) | (k & 3));
}
__device__ __forceinline__ void st_relax(float* p, float v){
  __hip_atomic_store(p, v, __ATOMIC_RELAXED, __HIP_MEMORY_SCOPE_AGENT);
}
__device__ __forceinline__ unsigned long long ld_relax8(const unsigned long long* p){
  return __hip_atomic_load(p, __ATOMIC_RELAXED, __HIP_MEMORY_SCOPE_AGENT);
}

// ---- tree barrier: arrive = 16 group counters (8 WGs) -> central;
//      detect = 16 leaders poll central -> per-group go-lines -> 7 followers each.
// Monotone counters/ordinals, no reset. arrive() after __syncthreads (drains stores).
__device__ __forceinline__ void arrive(int* g1, int* central, int wg){
  int v = __hip_atomic_fetch_add(&g1[(wg & 15) * 32], 1,
                                 __ATOMIC_ACQ_REL, __HIP_MEMORY_SCOPE_AGENT);
  if ((v & 7) == 7)   // completed this barrier's group-of-8
    __hip_atomic_fetch_add(central, 1, __ATOMIC_ACQ_REL, __HIP_MEMORY_SCOPE_AGENT);
}
// n-th barrier complete when central == 16*n. Leader (wg<16) broadcasts ordinal.
__device__ __forceinline__ void detect(const int* central, int* go, int wg, int n){
  if (wg < 16){
    while (__hip_atomic_load(central, __ATOMIC_ACQUIRE, __HIP_MEMORY_SCOPE_AGENT) < 16*n)
      __builtin_amdgcn_s_sleep(1);
    __hip_atomic_store(&go[wg * 32], n, __ATOMIC_RELEASE, __HIP_MEMORY_SCOPE_AGENT);
  } else {
    const int* gl = &go[(wg & 15) * 32];
    while (__hip_atomic_load(gl, __ATOMIC_ACQUIRE, __HIP_MEMORY_SCOPE_AGENT) < n)
      __builtin_amdgcn_s_sleep(1);
  }
}

// ---------- persistent serial lattice scan (all projections in-kernel) ----------
struct SLds {
  float Wh_l [12*512];
  float Wwh_l[12*512];
  float Wi_l [12*512];
  float Wwi_l[12*512];
  float Ah_l [4*512];
  float Ai_l [4*512];
  float h_l [H];
  float x_l [H];
  float we_l[W4*520];          // wemb(j-1) rows, padded stride
  float wcf [W4*520];          // full wc(j-1), padded stride
  float gh_l[12];
  float wgh_l[12];
  float gx_l[12];
  float awi_l[HS];
  float wgp_l[W4][12];
  float bmi_l[12];
  float bw_l [12];
  float bal_l[HS];
  float ring_c_l  [RINGN][W4][HS];
  float ring_awh_l[RINGN][W4][HS];
  float c_prev_l[HS];
  int ring_len_l[RINGN][W4];
  int ring_step_l[RINGN];
  int klen_l[W4];
};

__global__ __launch_bounds__(NTH) void lattice_serial(
    const float* __restrict__ xg,  const float* __restrict__ kbe,
    const int*   __restrict__ kblen,
    const float* __restrict__ Wi,  const float* __restrict__ Wh,
    const float* __restrict__ bmi, const float* __restrict__ Ai,
    const float* __restrict__ Ah,  const float* __restrict__ bal,
    const float* __restrict__ Wwi, const float* __restrict__ Wwh,
    const float* __restrict__ bw,
    float* hbuf, float* wcbuf,
    int* g1A, int* cenA, int* goA, int* g1C, int* cenC, int* goC,
    float* __restrict__ out, int T)
{
  __shared__ SLds S;
  const int tid  = threadIdx.x;
  const int wg   = blockIdx.x;
  const int base = wg * HS;

  // ---- stage weight column slices (f32, swizzled) ----
  for (int i = tid; i < 12*512; i += NTH){
    int d = i >> 9, k = i & 511;
    size_t gcol = (size_t)(d >> 2)*512 + base + (d & 3);
    S.Wh_l [swz(d,k)] = Wh [(size_t)k*1536 + gcol];
    S.Wwh_l[swz(d,k)] = Wwh[(size_t)k*1536 + gcol];
    S.Wi_l [swz(d,k)] = Wi [(size_t)k*1536 + gcol];
    S.Wwi_l[swz(d,k)] = Wwi[(size_t)k*1536 + gcol];
  }
  for (int i = tid; i < 4*512; i += NTH){
    int c = i >> 9, k = i & 511;
    S.Ah_l[swz(c,k)] = Ah[(size_t)k*512 + base + c];
    S.Ai_l[swz(c,k)] = Ai[(size_t)k*512 + base + c];
  }
  if (tid < 12){
    int gcol = (tid >> 2)*512 + base + (tid & 3);
    S.bmi_l[tid] = bmi[gcol];
    S.bw_l [tid] = bw [gcol];
  }
  if (tid >= 16 && tid < 16+HS) S.bal_l[tid-16] = bal[base + tid - 16];
  for (int i = tid; i < H; i += NTH){ S.h_l[i] = 0.f; S.x_l[i] = 0.f; }
  for (int i = tid; i < W4*520; i += NTH) S.we_l[i] = 0.f;
  for (int i = tid; i < RINGN*W4*HS; i += NTH){
    ((float*)S.ring_c_l)[i]   = 0.f;
    ((float*)S.ring_awh_l)[i] = 0.f;
  }
  if (tid < RINGN) S.ring_step_l[tid] = -2*RINGN;
  if (tid < RINGN*W4) ((int*)S.ring_len_l)[tid] = 0;
  if (tid < HS) S.c_prev_l[tid] = 0.f;
  __syncthreads();

  for (int j = 0; j < T; ++j){
    // ---- stage x(j), wemb(j-1), klen(j-1) (h-independent) ----
    {
      float xv0 = xg[(size_t)j*H + tid];
      float xv1 = xg[(size_t)j*H + NTH + tid];
      S.x_l[tid] = xv0; S.x_l[NTH + tid] = xv1;
      if (j > 0){
        #pragma unroll
        for (int r = 0; r < 8; ++r){
          int i = r*NTH + tid;
          S.we_l[(i >> 9)*520 + (i & 511)] = kbe[(size_t)(j-1)*(W4*H) + i];
        }
        if (tid < W4) S.klen_l[tid] = kblen[(size_t)(j-1)*W4 + tid];
      }
    }
    __syncthreads();

    // ---- PROJ (h-independent; overlaps the h-barrier latency):
    //      gx(j)=x·Wi, awi(j)=x·Ai, wgp(j-1)=wemb·Wwi  (64 dots, 2 passes) ----
    {
      const int sub = tid & 7;
      #pragma unroll
      for (int p = 0; p < 2; ++p){
        int dotid = p*32 + (tid >> 3);
        const float* Apt; const float* Wb; int row;
        if (dotid < 12)      { Apt = S.x_l; Wb = S.Wi_l; row = dotid; }
        else if (dotid < 16) { Apt = S.x_l; Wb = S.Ai_l; row = dotid - 12; }
        else { int q = dotid - 16; Apt = &S.we_l[(q/12)*520]; Wb = S.Wwi_l; row = q % 12; }
        float acc = 0.f;
        #pragma unroll
        for (int i2 = 0; i2 < 16; ++i2){
          int cch = (i2 << 3) | sub;
          const float4 a4 = *(const float4*)&Apt[cch << 2];
          const float4 w4 = *(const float4*)&Wb[(row << 9) + ((cch ^ (row & 7)) << 2)];
          acc = fmaf(a4.x, w4.x, acc);
          acc = fmaf(a4.y, w4.y, acc);
          acc = fmaf(a4.z, w4.z, acc);
          acc = fmaf(a4.w, w4.w, acc);
        }
        acc += __shfl_xor(acc, 1); acc += __shfl_xor(acc, 2); acc += __shfl_xor(acc, 4);
        if (sub == 0){
          if (dotid < 12)      S.gx_l[dotid]      = acc + S.bmi_l[dotid];
          else if (dotid < 16) S.awi_l[dotid-12]  = acc + S.bal_l[dotid-12];
          else { int q = dotid-16; S.wgp_l[q/12][q%12] = acc + S.bw_l[q%12]; }
        }
      }
    }

    // ---- detect h(j-1) published (C-barrier ordinal j); read it ----
    if (j > 0){
      if (tid == 192) detect(cenC, goC, wg, j);
      __syncthreads();
      ((unsigned long long*)S.h_l)[tid] = ld_relax8((const unsigned long long*)hbuf + tid);
    }
    __syncthreads();

    // ---- Phase A1: wgh(j-1) = h·Wwh cols (12 dots, tid<96) ----
    if (j > 0 && tid < 96){
      const int sub = tid & 7;
      int d = tid >> 3;
      float acc = 0.f;
      #pragma unroll
      for (int i2 = 0; i2 < 16; ++i2){
        int cch = (i2 << 3) | sub;
        const float4 hv  = *(const float4*)&S.h_l[cch << 2];
        const float4 wv4 = *(const float4*)&S.Wwh_l[(d << 9) + ((cch ^ (d & 7)) << 2)];
        acc = fmaf(hv.x, wv4.x, acc);
        acc = fmaf(hv.y, wv4.y, acc);
        acc = fmaf(hv.z, wv4.z, acc);
        acc = fmaf(hv.w, wv4.w, acc);
      }
      acc += __shfl_xor(acc, 1); acc += __shfl_xor(acc, 2); acc += __shfl_xor(acc, 4);
      if (sub == 0) S.wgh_l[d] = acc;
    }
    __syncthreads();

    if (j > 0){
      // ---- wc(j-1) local slice, publish; tree-arrive (A-barrier ordinal j) ----
      if (tid < W4*HS){
        int w = tid >> 2, e = tid & 3;
        float fr = S.wgp_l[w][e]   + S.wgh_l[e];
        float ir = S.wgp_l[w][4+e] + S.wgh_l[4+e];
        float gr = S.wgp_l[w][8+e] + S.wgh_l[8+e];
        float wcv = sigf(fr)*S.c_prev_l[e] + sigf(ir)*tanhft(gr);
        st_relax(&wcbuf[w*H + base + e], wcv);
      }
      __syncthreads();               // drain wc stores
      if (tid == 192) arrive(g1A, cenA, wg);
    }

    // ---- Phase A2: gh(j) = h·Wh cols (12 dots, tid<96) — overlaps A-barrier ----
    if (tid < 96){
      const int sub = tid & 7;
      int d = tid >> 3;
      float acc = 0.f;
      #pragma unroll
      for (int i2 = 0; i2 < 16; ++i2){
        int cch = (i2 << 3) | sub;
        const float4 hv  = *(const float4*)&S.h_l[cch << 2];
        const float4 wv4 = *(const float4*)&S.Wh_l[(d << 9) + ((cch ^ (d & 7)) << 2)];
        acc = fmaf(hv.x, wv4.x, acc);
        acc = fmaf(hv.y, wv4.y, acc);
        acc = fmaf(hv.z, wv4.z, acc);
        acc = fmaf(hv.w, wv4.w, acc);
      }
      acc += __shfl_xor(acc, 1); acc += __shfl_xor(acc, 2); acc += __shfl_xor(acc, 4);
      if (sub == 0) S.gh_l[d] = acc;
    }

    // ---- detect A-barrier; read full wc(j-1) ----
    if (j > 0){
      if (tid == 192) detect(cenA, goA, wg, j);
      __syncthreads();
      const unsigned long long* wb = (const unsigned long long*)wcbuf;
      #pragma unroll
      for (int r = 0; r < 4; ++r){
        int i = r*NTH + tid;                       // pair index 0..1023
        unsigned long long v = ld_relax8(&wb[i]);
        int w = i >> 8, k = (i & 255) << 1;
        *(unsigned long long*)&S.wcf[w*520 + k] = v;
      }
    }
    __syncthreads();

    // ---- Phase B: awh(j-1) slice = wc·Ah cols; ring update ----
    if (j > 0){
      const int s = (j-1) & 7;
      if (tid < 128){
        int dt = tid >> 3, sub = tid & 7;
        int w = dt >> 2, c = dt & 3;
        float acc = 0.f;
        #pragma unroll
        for (int i2 = 0; i2 < 16; ++i2){
          int cch = (i2 << 3) | sub;
          const float4 wv4 = *(const float4*)&S.wcf[w*520 + (cch << 2)];
          const float4 av  = *(const float4*)&S.Ah_l[(c << 9) + ((cch ^ (c & 7)) << 2)];
          acc = fmaf(wv4.x, av.x, acc);
          acc = fmaf(wv4.y, av.y, acc);
          acc = fmaf(wv4.z, av.z, acc);
          acc = fmaf(wv4.w, av.w, acc);
        }
        acc += __shfl_xor(acc, 1); acc += __shfl_xor(acc, 2); acc += __shfl_xor(acc, 4);
        if (sub == 0) S.ring_awh_l[s][w][c] = acc;
      }
      if (tid < W4*HS){ int w = tid >> 2, e = tid & 3; S.ring_c_l[s][w][e] = S.wcf[w*520 + base + e]; }
      if (tid < W4) S.ring_len_l[s][tid] = S.klen_l[tid];
      if (tid == 0) S.ring_step_l[s] = j-1;
    }
    __syncthreads();

    // ---- Phase C: part2(j) — fully local; publish h(j); tree-arrive ----
    if (tid < 128){
      int entry = tid & 31, e = tid >> 5;
      int s = entry >> 2, w = entry & 3;
      bool msk = (S.ring_step_l[s] + S.ring_len_l[s][w] - 1 == j);
      float aw = S.awi_l[e] + S.ring_awh_l[s][w][e];
      float ev  = msk ? __expf(sigf(aw)) : 0.f;
      float ecv = msk ? ev * S.ring_c_l[s][w][e] : 0.f;
      #pragma unroll
      for (int m = 1; m < 32; m <<= 1){
        ev  += __shfl_xor(ev,  m);
        ecv += __shfl_xor(ecv, m);
      }
      int anym = __any((int)msk);
      float ir  = S.gx_l[e]   + S.gh_l[e];
      float orr = S.gx_l[4+e] + S.gh_l[4+e];
      float gr  = S.gx_l[8+e] + S.gh_l[8+e];
      float i_g = sigf(ir), o_g = tanhft(orr), g_g = sigf(gr);
      float e_i = __expf(i_g);
      float c_new;
      if (anym) c_new = (e_i*g_g + ecv) / (e_i + ev);
      else      c_new = (1.f - i_g)*S.c_prev_l[e] + i_g*g_g;
      float h_new = o_g * tanhft(c_new);
      if (entry == 0){
        st_relax(&hbuf[base+e], h_new);
        out[(size_t)j*H + base + e]               = h_new;   // f32 store
        out[(size_t)T*H + (size_t)j*H + base + e] = c_new;   // f32 store
        S.c_prev_l[e] = c_new;
      }
    }
    __syncthreads();                 // drain h stores
    if (tid == 192) arrive(g1C, cenC, wg);   // C-barrier ordinal j+1; detected next step
  }
}

// ---------- launcher ----------
extern "C" void kernel_launch(void* const* d_in, const int* in_sizes, int n_in,
                              void* d_out, int out_size, void* d_ws, size_t ws_size,
                              hipStream_t stream)
{
  const float* x    = (const float*)d_in[0];
  const float* kbe  = (const float*)d_in[1];
  const int*   kblen= (const int*)d_in[2];
  const float* Wi   = (const float*)d_in[3];
  const float* Wh   = (const float*)d_in[4];
  const float* bmi  = (const float*)d_in[5];
  const float* Ai   = (const float*)d_in[6];
  const float* Ah   = (const float*)d_in[7];
  const float* bal  = (const float*)d_in[8];
  const float* Wwi  = (const float*)d_in[9];
  const float* Wwh  = (const float*)d_in[10];
  const float* bw   = (const float*)d_in[11];
  const int T = in_sizes[0] / H;     // 1024
  float* out = (float*)d_out;        // reference output dtype = float32

  // workspace: hbuf[512] | wcbuf[2048] | g1A[512] cenA[32] goA[512] | g1C[512] cenC[32] goC[512]
  float* ws    = (float*)d_ws;
  float* hbuf  = ws;
  float* wcbuf = hbuf + 512;
  int*   g1A   = (int*)(wcbuf + 2048);
  int*   cenA  = g1A + 16*32;
  int*   goA   = cenA + 32;
  int*   g1C   = goA + 16*32;
  int*   cenC  = g1C + 16*32;
  int*   goC   = cenC + 32;

  (void)hipMemsetAsync(g1A, 0, (size_t)(3*(16*32) + 2*32 + 16*32)*sizeof(int), stream);

  lattice_serial<<<NWG, NTH, 0, stream>>>(x, kbe, kblen, Wi, Wh, bmi, Ai, Ah, bal,
                                          Wwi, Wwh, bw, hbuf, wcbuf,
                                          g1A, cenA, goA, g1C, cenC, goC, out, T);
}

// Round 16
// 15141.628 us; speedup vs baseline: 1.4140x; 1.4140x over previous
//
#include <hip/hip_runtime.h>

#define H 512
#define W4 4
#define RINGN 8
#define NWG 128
#define HS 4          // H / NWG
#define NTH 256

// ---------- helpers ----------
__device__ __forceinline__ float sigf(float x){ return 1.f/(1.f+__expf(-x)); }
__device__ __forceinline__ float tanhft(float x){
  float t = __expf(-2.f*fabsf(x));      // never overflows
  float r = (1.f - t)/(1.f + t);
  return copysignf(r, x);
}
// swizzled LDS element index for column-major weight slices
__device__ __forceinline__ int swz(int dd, int k){
  return (dd << 9) | ((((k >> 2) ^ (dd & 7)) << 2) | (k & 3));
}
__device__ __forceinline__ void st_relax(float* p, float v){
  __hip_atomic_store(p, v, __ATOMIC_RELAXED, __HIP_MEMORY_SCOPE_AGENT);
}
__device__ __forceinline__ unsigned long long ld_relax8(const unsigned long long* p){
  return __hip_atomic_load(p, __ATOMIC_RELAXED, __HIP_MEMORY_SCOPE_AGENT);
}

// ---- flat central-counter barrier (minimum IC hops), split arrive/detect ----
// monotone per-step counters (cnt[2T], memset once). Call arrive() from ONE
// thread after __syncthreads (drains this WG's stores); detect() from one
// thread, then __syncthreads before reading the synced data.
__device__ __forceinline__ void arrive(int* c){
  __hip_atomic_fetch_add(c, 1, __ATOMIC_ACQ_REL, __HIP_MEMORY_SCOPE_AGENT);
}
__device__ __forceinline__ void detect(const int* c){
  while (__hip_atomic_load(c, __ATOMIC_ACQUIRE, __HIP_MEMORY_SCOPE_AGENT) < NWG)
    __builtin_amdgcn_s_sleep(2);
}

// ---------- persistent serial lattice scan (all projections in-kernel) ----------
struct SLds {
  float Wh_l [12*512];
  float Wwh_l[12*512];
  float Wi_l [12*512];
  float Wwi_l[12*512];
  float Ah_l [4*512];
  float Ai_l [4*512];
  float h_l [H];
  float x_l [H];
  float we_l[W4*520];          // wemb(j-1) rows, padded stride
  float wcf [W4*520];          // full wc(j-1), padded stride
  float gh_l[12];
  float wgh_l[12];
  float gx_l[12];
  float awi_l[HS];
  float wgp_l[W4][12];
  float bmi_l[12];
  float bw_l [12];
  float bal_l[HS];
  float ring_c_l  [RINGN][W4][HS];
  float ring_awh_l[RINGN][W4][HS];
  float c_prev_l[HS];
  int ring_len_l[RINGN][W4];
  int ring_step_l[RINGN];
  int klen_l[W4];
};

__global__ __launch_bounds__(NTH) void lattice_serial(
    const float* __restrict__ xg,  const float* __restrict__ kbe,
    const int*   __restrict__ kblen,
    const float* __restrict__ Wi,  const float* __restrict__ Wh,
    const float* __restrict__ bmi, const float* __restrict__ Ai,
    const float* __restrict__ Ah,  const float* __restrict__ bal,
    const float* __restrict__ Wwi, const float* __restrict__ Wwh,
    const float* __restrict__ bw,
    float* hbuf, float* wcbuf, int* cnt,
    float* __restrict__ out, int T)
{
  __shared__ SLds S;
  const int tid  = threadIdx.x;
  const int wg   = blockIdx.x;
  const int base = wg * HS;

  // ---- stage weight column slices (f32, swizzled) ----
  for (int i = tid; i < 12*512; i += NTH){
    int d = i >> 9, k = i & 511;
    size_t gcol = (size_t)(d >> 2)*512 + base + (d & 3);
    S.Wh_l [swz(d,k)] = Wh [(size_t)k*1536 + gcol];
    S.Wwh_l[swz(d,k)] = Wwh[(size_t)k*1536 + gcol];
    S.Wi_l [swz(d,k)] = Wi [(size_t)k*1536 + gcol];
    S.Wwi_l[swz(d,k)] = Wwi[(size_t)k*1536 + gcol];
  }
  for (int i = tid; i < 4*512; i += NTH){
    int c = i >> 9, k = i & 511;
    S.Ah_l[swz(c,k)] = Ah[(size_t)k*512 + base + c];
    S.Ai_l[swz(c,k)] = Ai[(size_t)k*512 + base + c];
  }
  if (tid < 12){
    int gcol = (tid >> 2)*512 + base + (tid & 3);
    S.bmi_l[tid] = bmi[gcol];
    S.bw_l [tid] = bw [gcol];
  }
  if (tid >= 16 && tid < 16+HS) S.bal_l[tid-16] = bal[base + tid - 16];
  for (int i = tid; i < H; i += NTH){ S.h_l[i] = 0.f; S.x_l[i] = 0.f; }
  for (int i = tid; i < W4*520; i += NTH) S.we_l[i] = 0.f;
  for (int i = tid; i < RINGN*W4*HS; i += NTH){
    ((float*)S.ring_c_l)[i]   = 0.f;
    ((float*)S.ring_awh_l)[i] = 0.f;
  }
  if (tid < RINGN) S.ring_step_l[tid] = -2*RINGN;
  if (tid < RINGN*W4) ((int*)S.ring_len_l)[tid] = 0;
  if (tid < HS) S.c_prev_l[tid] = 0.f;
  __syncthreads();

  for (int j = 0; j < T; ++j){
    // ---- stage x(j), wemb(j-1), klen(j-1) (h-independent) ----
    {
      float xv0 = xg[(size_t)j*H + tid];
      float xv1 = xg[(size_t)j*H + NTH + tid];
      S.x_l[tid] = xv0; S.x_l[NTH + tid] = xv1;
      if (j > 0){
        #pragma unroll
        for (int r = 0; r < 8; ++r){
          int i = r*NTH + tid;
          S.we_l[(i >> 9)*520 + (i & 511)] = kbe[(size_t)(j-1)*(W4*H) + i];
        }
        if (tid < W4) S.klen_l[tid] = kblen[(size_t)(j-1)*W4 + tid];
      }
    }
    __syncthreads();

    // ---- PROJ (h-independent; hides the C-barrier detect latency):
    //      gx(j)=x·Wi, awi(j)=x·Ai, wgp(j-1)=wemb·Wwi  (64 dots, 2 passes) ----
    {
      const int sub = tid & 7;
      #pragma unroll
      for (int p = 0; p < 2; ++p){
        int dotid = p*32 + (tid >> 3);
        const float* Apt; const float* Wb; int row;
        if (dotid < 12)      { Apt = S.x_l; Wb = S.Wi_l; row = dotid; }
        else if (dotid < 16) { Apt = S.x_l; Wb = S.Ai_l; row = dotid - 12; }
        else { int q = dotid - 16; Apt = &S.we_l[(q/12)*520]; Wb = S.Wwi_l; row = q % 12; }
        float acc = 0.f;
        #pragma unroll
        for (int i2 = 0; i2 < 16; ++i2){
          int cch = (i2 << 3) | sub;
          const float4 a4 = *(const float4*)&Apt[cch << 2];
          const float4 w4 = *(const float4*)&Wb[(row << 9) + ((cch ^ (row & 7)) << 2)];
          acc = fmaf(a4.x, w4.x, acc);
          acc = fmaf(a4.y, w4.y, acc);
          acc = fmaf(a4.z, w4.z, acc);
          acc = fmaf(a4.w, w4.w, acc);
        }
        acc += __shfl_xor(acc, 1); acc += __shfl_xor(acc, 2); acc += __shfl_xor(acc, 4);
        if (sub == 0){
          if (dotid < 12)      S.gx_l[dotid]      = acc + S.bmi_l[dotid];
          else if (dotid < 16) S.awi_l[dotid-12]  = acc + S.bal_l[dotid-12];
          else { int q = dotid-16; S.wgp_l[q/12][q%12] = acc + S.bw_l[q%12]; }
        }
      }
    }

    // ---- detect h(j-1) published (C-counter of step j-1); read it ----
    if (j > 0){
      if (tid == 192) detect(&cnt[2*j - 1]);
      __syncthreads();
      ((unsigned long long*)S.h_l)[tid] = ld_relax8((const unsigned long long*)hbuf + tid);
    }
    __syncthreads();

    // ---- Phase A1: wgh(j-1) = h·Wwh cols (12 dots, tid<96) ----
    if (j > 0 && tid < 96){
      const int sub = tid & 7;
      int d = tid >> 3;
      float acc = 0.f;
      #pragma unroll
      for (int i2 = 0; i2 < 16; ++i2){
        int cch = (i2 << 3) | sub;
        const float4 hv  = *(const float4*)&S.h_l[cch << 2];
        const float4 wv4 = *(const float4*)&S.Wwh_l[(d << 9) + ((cch ^ (d & 7)) << 2)];
        acc = fmaf(hv.x, wv4.x, acc);
        acc = fmaf(hv.y, wv4.y, acc);
        acc = fmaf(hv.z, wv4.z, acc);
        acc = fmaf(hv.w, wv4.w, acc);
      }
      acc += __shfl_xor(acc, 1); acc += __shfl_xor(acc, 2); acc += __shfl_xor(acc, 4);
      if (sub == 0) S.wgh_l[d] = acc;
    }
    __syncthreads();

    if (j > 0){
      // ---- wc(j-1) local slice, publish; flat-arrive (A-counter, step j) ----
      if (tid < W4*HS){
        int w = tid >> 2, e = tid & 3;
        float fr = S.wgp_l[w][e]   + S.wgh_l[e];
        float ir = S.wgp_l[w][4+e] + S.wgh_l[4+e];
        float gr = S.wgp_l[w][8+e] + S.wgh_l[8+e];
        float wcv = sigf(fr)*S.c_prev_l[e] + sigf(ir)*tanhft(gr);
        st_relax(&wcbuf[w*H + base + e], wcv);
      }
      __syncthreads();               // drain wc stores
      if (tid == 192) arrive(&cnt[2*j]);
    }

    // ---- Phase A2: gh(j) = h·Wh cols (12 dots, tid<96) — hides A-barrier ----
    if (tid < 96){
      const int sub = tid & 7;
      int d = tid >> 3;
      float acc = 0.f;
      #pragma unroll
      for (int i2 = 0; i2 < 16; ++i2){
        int cch = (i2 << 3) | sub;
        const float4 hv  = *(const float4*)&S.h_l[cch << 2];
        const float4 wv4 = *(const float4*)&S.Wh_l[(d << 9) + ((cch ^ (d & 7)) << 2)];
        acc = fmaf(hv.x, wv4.x, acc);
        acc = fmaf(hv.y, wv4.y, acc);
        acc = fmaf(hv.z, wv4.z, acc);
        acc = fmaf(hv.w, wv4.w, acc);
      }
      acc += __shfl_xor(acc, 1); acc += __shfl_xor(acc, 2); acc += __shfl_xor(acc, 4);
      if (sub == 0) S.gh_l[d] = acc;
    }

    // ---- detect A-counter; read full wc(j-1) ----
    if (j > 0){
      if (tid == 192) detect(&cnt[2*j]);
      __syncthreads();
      const unsigned long long* wb = (const unsigned long long*)wcbuf;
      #pragma unroll
      for (int r = 0; r < 4; ++r){
        int i = r*NTH + tid;                       // pair index 0..1023
        unsigned long long v = ld_relax8(&wb[i]);
        int w = i >> 8, k = (i & 255) << 1;
        *(unsigned long long*)&S.wcf[w*520 + k] = v;
      }
    }
    __syncthreads();

    // ---- Phase B: awh(j-1) slice = wc·Ah cols; ring update ----
    if (j > 0){
      const int s = (j-1) & 7;
      if (tid < 128){
        int dt = tid >> 3, sub = tid & 7;
        int w = dt >> 2, c = dt & 3;
        float acc = 0.f;
        #pragma unroll
        for (int i2 = 0; i2 < 16; ++i2){
          int cch = (i2 << 3) | sub;
          const float4 wv4 = *(const float4*)&S.wcf[w*520 + (cch << 2)];
          const float4 av  = *(const float4*)&S.Ah_l[(c << 9) + ((cch ^ (c & 7)) << 2)];
          acc = fmaf(wv4.x, av.x, acc);
          acc = fmaf(wv4.y, av.y, acc);
          acc = fmaf(wv4.z, av.z, acc);
          acc = fmaf(wv4.w, av.w, acc);
        }
        acc += __shfl_xor(acc, 1); acc += __shfl_xor(acc, 2); acc += __shfl_xor(acc, 4);
        if (sub == 0) S.ring_awh_l[s][w][c] = acc;
      }
      if (tid < W4*HS){ int w = tid >> 2, e = tid & 3; S.ring_c_l[s][w][e] = S.wcf[w*520 + base + e]; }
      if (tid < W4) S.ring_len_l[s][tid] = S.klen_l[tid];
      if (tid == 0) S.ring_step_l[s] = j-1;
    }
    __syncthreads();

    // ---- Phase C: part2(j) — fully local; publish h(j); flat-arrive ----
    if (tid < 128){
      int entry = tid & 31, e = tid >> 5;
      int s = entry >> 2, w = entry & 3;
      bool msk = (S.ring_step_l[s] + S.ring_len_l[s][w] - 1 == j);
      float aw = S.awi_l[e] + S.ring_awh_l[s][w][e];
      float ev  = msk ? __expf(sigf(aw)) : 0.f;
      float ecv = msk ? ev * S.ring_c_l[s][w][e] : 0.f;
      #pragma unroll
      for (int m = 1; m < 32; m <<= 1){
        ev  += __shfl_xor(ev,  m);
        ecv += __shfl_xor(ecv, m);
      }
      int anym = __any((int)msk);
      float ir  = S.gx_l[e]   + S.gh_l[e];
      float orr = S.gx_l[4+e] + S.gh_l[4+e];
      float gr  = S.gx_l[8+e] + S.gh_l[8+e];
      float i_g = sigf(ir), o_g = tanhft(orr), g_g = sigf(gr);
      float e_i = __expf(i_g);
      float c_new;
      if (anym) c_new = (e_i*g_g + ecv) / (e_i + ev);
      else      c_new = (1.f - i_g)*S.c_prev_l[e] + i_g*g_g;
      float h_new = o_g * tanhft(c_new);
      if (entry == 0){
        st_relax(&hbuf[base+e], h_new);
        out[(size_t)j*H + base + e]               = h_new;   // f32 store
        out[(size_t)T*H + (size_t)j*H + base + e] = c_new;   // f32 store
        S.c_prev_l[e] = c_new;
      }
    }
    __syncthreads();                 // drain h stores
    if (tid == 192) arrive(&cnt[2*j + 1]);   // C-counter of step j; detected next step
  }
}

// ---------- launcher ----------
extern "C" void kernel_launch(void* const* d_in, const int* in_sizes, int n_in,
                              void* d_out, int out_size, void* d_ws, size_t ws_size,
                              hipStream_t stream)
{
  const float* x    = (const float*)d_in[0];
  const float* kbe  = (const float*)d_in[1];
  const int*   kblen= (const int*)d_in[2];
  const float* Wi   = (const float*)d_in[3];
  const float* Wh   = (const float*)d_in[4];
  const float* bmi  = (const float*)d_in[5];
  const float* Ai   = (const float*)d_in[6];
  const float* Ah   = (const float*)d_in[7];
  const float* bal  = (const float*)d_in[8];
  const float* Wwi  = (const float*)d_in[9];
  const float* Wwh  = (const float*)d_in[10];
  const float* bw   = (const float*)d_in[11];
  const int T = in_sizes[0] / H;     // 1024
  float* out = (float*)d_out;        // reference output dtype = float32

  // workspace: hbuf[512] | wcbuf[2048] | cnt[2*T]
  float* ws    = (float*)d_ws;
  float* hbuf  = ws;
  float* wcbuf = hbuf + 512;
  int*   cnt   = (int*)(wcbuf + 2048);

  (void)hipMemsetAsync(cnt, 0, (size_t)2*T*sizeof(int), stream);

  lattice_serial<<<NWG, NTH, 0, stream>>>(x, kbe, kblen, Wi, Wh, bmi, Ai, Ah, bal,
                                          Wwi, Wwh, bw, hbuf, wcbuf, cnt, out, T);
}